// Round 7
// baseline (215.446 us; speedup 1.0000x reference)
//
#include <hip/hip_runtime.h>

// ---------------------------------------------------------------------------
// GNN 2-layer via bf16 MFMA + CSR gather (no global atomics).
// Round 7 = Round-6 + parallelized CSR build:
//  - binD: 4 sub-blocks per coarse bucket (784 blocks, ~3/CU vs 196 blocks
//    = 0.77/CU). Each sub re-reads the bucket, builds 4 quarter-histograms,
//    scatters its quarter at start offset sum(h[q<sub]). outS staging dropped
//    (scattered 4B writes within 16KB window merge in L2); no DCAP limit.
//  - binA/binC: CBLK 256 -> 512 blocks (half the serial atomics per block);
//    binB cursor scan widened to 512 via pair-per-thread scan.
// Launches:
//   K1: pack_w || binA
//   K2: binB (merged scans)
//   K3: binC || gemm1[0..gbA)
//   K4: binD(x4 subs) || gemm1[gbA..)
//   K5: gather_bf (layer 1) -> agg1bf (bf16)
//   K6: gemm2_mfma -> out[:,128:] fp32 + m2bf
//   K7: gather_bf (layer 2) -> out[:, :128] fp32
// ws: m1bf | agg1bf | m2bf | W1p | W2p | mat | matc | bb | offs | tmp | bsrc
// ---------------------------------------------------------------------------

#define D 128
#define CBLK 512         // coarse-binning blocks (phases A and C)

typedef __attribute__((ext_vector_type(8))) short short8;
typedef __attribute__((ext_vector_type(4))) float float4v;
typedef unsigned short ushort_t;
typedef unsigned int uint_t;

static __device__ __forceinline__ ushort_t f2bf(float f) {
    uint_t u = __builtin_bit_cast(uint_t, f);
    u += 0x7FFFu + ((u >> 16) & 1u);           // RNE
    return (ushort_t)(u >> 16);
}
static __device__ __forceinline__ float bfhi(uint_t u) {
    return __builtin_bit_cast(float, u & 0xFFFF0000u);
}
static __device__ __forceinline__ float bflo(uint_t u) {
    return __builtin_bit_cast(float, u << 16);
}

// ---------------- shared gemm1 body: 64-row tile, wave = 16 rows ------------
static __device__ __forceinline__ void gemm1_body(
    const float* __restrict__ X, const ushort_t* __restrict__ Wp,
    const float* __restrict__ bias, ushort_t* __restrict__ Ybf,
    int N, int gb)
{
    const int wave = threadIdx.x >> 6;
    const int lane = threadIdx.x & 63;
    const int quad = lane >> 4;
    const int l16  = lane & 15;
    const int r0   = gb * 64 + wave * 16;

    float4v acc[8];
    #pragma unroll
    for (int cg = 0; cg < 8; ++cg) {
        float bv = bias[cg * 16 + l16];
        float4v b4 = {bv, bv, bv, bv};
        acc[cg] = b4;
    }

    const short8* wp8 = (const short8*)Wp;

    #pragma unroll
    for (int kb = 0; kb < 4; ++kb) {
        const int k0 = kb * 32 + quad * 8;
        int row = r0 + l16;
        if (row >= N) row = N - 1;
        const float* p = &X[(size_t)row * D + k0];
        float4 x0 = *(const float4*)p;
        float4 x1 = *(const float4*)(p + 4);
        short8 a;
        a[0] = (short)f2bf(x0.x); a[1] = (short)f2bf(x0.y);
        a[2] = (short)f2bf(x0.z); a[3] = (short)f2bf(x0.w);
        a[4] = (short)f2bf(x1.x); a[5] = (short)f2bf(x1.y);
        a[6] = (short)f2bf(x1.z); a[7] = (short)f2bf(x1.w);
        #pragma unroll
        for (int cg = 0; cg < 8; ++cg) {
            short8 b = wp8[(kb * 8 + cg) * 64 + lane];
            acc[cg] = __builtin_amdgcn_mfma_f32_16x16x32_bf16(a, b, acc[cg], 0, 0, 0);
        }
    }

    const int rowb = r0 + quad * 4;
    #pragma unroll
    for (int cg = 0; cg < 8; ++cg) {
        int col = cg * 16 + l16;
        #pragma unroll
        for (int i = 0; i < 4; ++i) {
            int row = rowb + i;
            if (row < N) Ybf[(size_t)row * D + col] = f2bf(acc[cg][i]);
        }
    }
}

// ---------------- K1: pack both W (B-frag layout)  ||  binA -----------------
__global__ __launch_bounds__(256) void packw_binA(
    const float* __restrict__ W1, const float* __restrict__ W2,
    ushort_t* __restrict__ W1p, ushort_t* __restrict__ W2p,
    const int* __restrict__ dst, int* __restrict__ mat, int E, int NB)
{
    __shared__ int h[256];
    if (blockIdx.x < CBLK) {
        const int c = blockIdx.x;
        for (int i = threadIdx.x; i < NB; i += 256) h[i] = 0;
        __syncthreads();
        const int chunk = (E + CBLK - 1) / CBLK;
        int e0 = c * chunk, e1 = e0 + chunk; if (e1 > E) e1 = E;
        for (int e = e0 + threadIdx.x; e < e1; e += 256)
            atomicAdd(&h[dst[e] >> 8], 1);
        __syncthreads();
        for (int i = threadIdx.x; i < NB; i += 256)
            mat[i * CBLK + c] = h[i];
        return;
    }
    const int n1 = 4 * 8 * 64;
    const int n2 = 8 * 8 * 64;
    int t = (blockIdx.x - CBLK) * 256 + threadIdx.x;
    if (t >= n1 + n2) return;
    const float* W; ushort_t* Wp; int tt;
    if (t < n1) { W = W1; Wp = W1p; tt = t; }
    else        { W = W2; Wp = W2p; tt = t - n1; }
    int lane = tt & 63, cg = (tt >> 6) & 7, kb = tt >> 9;
    int krow = kb * 32 + (lane >> 4) * 8;
    int col  = cg * 16 + (lane & 15);
    #pragma unroll
    for (int j = 0; j < 8; ++j)
        Wp[(size_t)tt * 8 + j] = f2bf(W[(size_t)(krow + j) * D + col]);
}

// ---------------- K2: binB (merged scans, 512-wide cursor phase) ------------
__global__ __launch_bounds__(256) void binB(
    const int* __restrict__ mat, int* __restrict__ matc,
    int* __restrict__ bb, int* __restrict__ offs, int E, int N, int NB)
{
    __shared__ int s[256];
    __shared__ int ex[256];
    const int b = blockIdx.x;
    const int tid = threadIdx.x;

    // bucket totals (thread t sums bucket t's row of CBLK counts) + scan
    int v = 0;
    if (tid < NB) {
        const int* row = &mat[tid * CBLK];
        for (int c = 0; c < CBLK; ++c) v += row[c];
    }
    s[tid] = v; __syncthreads();
    for (int o = 1; o < 256; o <<= 1) {
        int t = (tid >= o) ? s[tid - o] : 0;
        __syncthreads();
        s[tid] += t;
        __syncthreads();
    }
    ex[tid] = s[tid] - v;
    __syncthreads();
    if (b == 0) {
        if (tid < NB) bb[tid] = ex[tid];
        if (tid == 0) { bb[NB] = E; offs[N] = E; }
    }
    const int bbb = ex[b];

    // cursor phase: exclusive scan of row b (512 entries, pair per thread)
    int v0 = mat[b * CBLK + 2 * tid];
    int v1 = mat[b * CBLK + 2 * tid + 1];
    int pair = v0 + v1;
    __syncthreads();
    s[tid] = pair; __syncthreads();
    for (int o = 1; o < 256; o <<= 1) {
        int t = (tid >= o) ? s[tid - o] : 0;
        __syncthreads();
        s[tid] += t;
        __syncthreads();
    }
    int base = s[tid] - pair;                 // exclusive prefix of pairs
    matc[b * CBLK + 2 * tid]     = bbb + base;
    matc[b * CBLK + 2 * tid + 1] = bbb + base + v0;
}

// ---------------- K3: binC  ||  gemm1 part A --------------------------------
__global__ __launch_bounds__(256) void binC_gemm1(
    const int* __restrict__ src, const int* __restrict__ dst,
    const int* __restrict__ matc, int2* __restrict__ tmp, int E, int NB,
    const float* __restrict__ X, const ushort_t* __restrict__ Wp,
    const float* __restrict__ bias, ushort_t* __restrict__ Ybf, int N)
{
    __shared__ int base[256];
    __shared__ int lcnt[256];
    if (blockIdx.x < CBLK) {
        const int c = blockIdx.x;
        for (int i = threadIdx.x; i < NB; i += 256) {
            base[i] = matc[i * CBLK + c];
            lcnt[i] = 0;
        }
        __syncthreads();
        const int chunk = (E + CBLK - 1) / CBLK;
        int e0 = c * chunk, e1 = e0 + chunk; if (e1 > E) e1 = E;
        for (int e = e0 + threadIdx.x; e < e1; e += 256) {
            int d = dst[e];
            int b = d >> 8;
            int p = base[b] + atomicAdd(&lcnt[b], 1);
            int2 pr; pr.x = d; pr.y = src[e];
            tmp[p] = pr;
        }
        return;
    }
    gemm1_body(X, Wp, bias, Ybf, N, blockIdx.x - CBLK);
}

// ---------------- K4: binD (fine sort, 4 subs/bucket) || gemm1 part B -------
// Sub-block s of bucket b: builds 4 quarter-histograms over the full bucket,
// scans the sum for per-node offsets, then scatters only its quarter with
// cursors starting at sum(h[q<s]). Direct global writes (L2 merges 4B
// scatters within the 16KB bucket window); no LDS staging, no size cap.
__global__ __launch_bounds__(256) void binD_gemm1(
    const int2* __restrict__ tmp, const int* __restrict__ bb,
    int* __restrict__ offs, int* __restrict__ bsrc, int N, int NB,
    const float* __restrict__ X, const ushort_t* __restrict__ Wp,
    const float* __restrict__ bias, ushort_t* __restrict__ Ybf, int gb0)
{
    __shared__ int h[4][256];
    __shared__ int sc[256];
    __shared__ int foff[256];
    __shared__ int cntf[256];
    if (blockIdx.x >= (uint_t)(NB * 4)) {
        gemm1_body(X, Wp, bias, Ybf, N, blockIdx.x - NB * 4 + gb0);
        return;
    }
    const int b   = blockIdx.x >> 2;
    const int sub = blockIdx.x & 3;
    const int tid = threadIdx.x;
    const int beg = bb[b], end = bb[b + 1];
    const int cnt = end - beg;
    const int n0 = b << 8;

    h[0][tid] = 0; h[1][tid] = 0; h[2][tid] = 0; h[3][tid] = 0;
    __syncthreads();

    const int c1 = cnt >> 2, c2 = cnt >> 1, c3 = cnt - (cnt >> 2);
    for (int i = tid; i < cnt; i += 256) {
        int f = tmp[beg + i].x & 255;
        int q = (i >= c1) + (i >= c2) + (i >= c3);
        atomicAdd(&h[q][f], 1);
    }
    __syncthreads();

    int v = h[0][tid] + h[1][tid] + h[2][tid] + h[3][tid];
    int start = 0;
    if (sub > 0) start += h[0][tid];
    if (sub > 1) start += h[1][tid];
    if (sub > 2) start += h[2][tid];
    cntf[tid] = start;

    sc[tid] = v; __syncthreads();
    for (int o = 1; o < 256; o <<= 1) {
        int t = (tid >= o) ? sc[tid - o] : 0;
        __syncthreads();
        sc[tid] += t;
        __syncthreads();
    }
    foff[tid] = sc[tid] - v;
    __syncthreads();

    int node = n0 + tid;
    if (sub == 0 && node < N) offs[node] = beg + foff[tid];

    const int s0 = (sub == 0) ? 0  : ((sub == 1) ? c1 : ((sub == 2) ? c2 : c3));
    const int s1 = (sub == 0) ? c1 : ((sub == 1) ? c2 : ((sub == 2) ? c3 : cnt));
    for (int i = s0 + tid; i < s1; i += 256) {
        int2 p = tmp[beg + i];
        int f = p.x & 255;
        int pos = foff[f] + atomicAdd(&cntf[f], 1);
        bsrc[beg + pos] = p.y;
    }
}

// ---------------- K6: MFMA GEMM 2 (64-row tile): bf16 A0/A1 -> fp32 + bf16 --
__global__ __launch_bounds__(256) void gemm2_mfma(
    const ushort_t* __restrict__ A0, const ushort_t* __restrict__ A1,
    const ushort_t* __restrict__ Wp, const float* __restrict__ bias,
    float* __restrict__ Yf, ushort_t* __restrict__ Ybf, int N)
{
    const int wave = threadIdx.x >> 6;
    const int lane = threadIdx.x & 63;
    const int quad = lane >> 4;
    const int l16  = lane & 15;
    const int r0   = blockIdx.x * 64 + wave * 16;

    float4v acc[8];
    #pragma unroll
    for (int cg = 0; cg < 8; ++cg) {
        float bv = bias[cg * 16 + l16];
        float4v b4 = {bv, bv, bv, bv};
        acc[cg] = b4;
    }

    const short8* wp8 = (const short8*)Wp;

    #pragma unroll
    for (int kb = 0; kb < 8; ++kb) {
        const ushort_t* __restrict__ A = (kb < 4) ? A0 : A1;
        const int k0 = (kb & 3) * 32 + quad * 8;
        int row = r0 + l16;
        if (row >= N) row = N - 1;
        short8 a = *(const short8*)&A[(size_t)row * D + k0];
        #pragma unroll
        for (int cg = 0; cg < 8; ++cg) {
            short8 b = wp8[(kb * 8 + cg) * 64 + lane];
            acc[cg] = __builtin_amdgcn_mfma_f32_16x16x32_bf16(a, b, acc[cg], 0, 0, 0);
        }
    }

    const int rowb = r0 + quad * 4;
    #pragma unroll
    for (int cg = 0; cg < 8; ++cg) {
        int col = cg * 16 + l16;
        #pragma unroll
        for (int i = 0; i < 4; ++i) {
            int row = rowb + i;
            if (row < N) {
                float v = acc[cg][i];
                Yf[(size_t)row * 256 + col] = v;
                Ybf[(size_t)row * D + col] = f2bf(v);
            }
        }
    }
}

// ---------------- K5/K7: gather-sum over CSR (bf16 msg), quad-split ---------
__global__ __launch_bounds__(256) void gather_bf(
    const ushort_t* __restrict__ msg,            // [N][128] bf16
    const int* __restrict__ offs, const int* __restrict__ bsrc,
    ushort_t* __restrict__ aggB,                 // bf16 out [N][128], or null
    float* __restrict__ aggF,                    // fp32 out (stride 256), or null
    int N)
{
    int node = (blockIdx.x * 256 + threadIdx.x) >> 6;
    int lane = threadIdx.x & 63;
    if (node >= N) return;
    const int quad = lane >> 4;
    const int c16  = lane & 15;
    int beg = offs[node], end = offs[node + 1];

    float ax[4] = {0.f, 0.f, 0.f, 0.f};
    float ay[4] = {0.f, 0.f, 0.f, 0.f};
    const uint4* mp = (const uint4*)msg;         // 16 uint4 per row

    for (int base = beg; base < end; base += 64) {
        int cnt = end - base; if (cnt > 64) cnt = 64;
        int sidx = bsrc[base + (lane < cnt ? lane : cnt - 1)];
        for (int j0 = 0; j0 < cnt; j0 += 16) {
            #pragma unroll
            for (int t = 0; t < 4; ++t) {
                int e  = j0 + t * 4 + quad;
                int ec = (e < cnt) ? e : cnt - 1;
                int s  = __shfl(sidx, ec, 64);
                uint4 u = mp[(size_t)s * 16 + c16];
                if (e < cnt) {
                    ax[0] += bflo(u.x); ay[0] += bfhi(u.x);
                    ax[1] += bflo(u.y); ay[1] += bfhi(u.y);
                    ax[2] += bflo(u.z); ay[2] += bfhi(u.z);
                    ax[3] += bflo(u.w); ay[3] += bfhi(u.w);
                }
            }
        }
    }

    #pragma unroll
    for (int k = 0; k < 4; ++k) {
        ax[k] += __shfl_xor(ax[k], 16, 64);
        ax[k] += __shfl_xor(ax[k], 32, 64);
        ay[k] += __shfl_xor(ay[k], 16, 64);
        ay[k] += __shfl_xor(ay[k], 32, 64);
    }

    if (quad == 0) {
        if (aggB) {
            uint4 o;
            o.x = (uint_t)f2bf(ax[0]) | ((uint_t)f2bf(ay[0]) << 16);
            o.y = (uint_t)f2bf(ax[1]) | ((uint_t)f2bf(ay[1]) << 16);
            o.z = (uint_t)f2bf(ax[2]) | ((uint_t)f2bf(ay[2]) << 16);
            o.w = (uint_t)f2bf(ax[3]) | ((uint_t)f2bf(ay[3]) << 16);
            ((uint4*)aggB)[(size_t)node * 16 + c16] = o;
        } else {
            float4 w0 = {ax[0], ay[0], ax[1], ay[1]};
            float4 w1 = {ax[2], ay[2], ax[3], ay[3]};
            float* p = &aggF[(size_t)node * 256 + c16 * 8];
            *(float4*)p = w0;
            *(float4*)(p + 4) = w1;
        }
    }
}

// ---------------------------------------------------------------------------
extern "C" void kernel_launch(void* const* d_in, const int* in_sizes, int n_in,
                              void* d_out, int out_size, void* d_ws, size_t ws_size,
                              hipStream_t stream) {
    const float* features = (const float*)d_in[0];
    const int*   src      = (const int*)d_in[1];
    const int*   dst      = (const int*)d_in[2];
    const float* W1       = (const float*)d_in[3];
    const float* b1       = (const float*)d_in[4];
    const float* W2       = (const float*)d_in[5];
    const float* b2       = (const float*)d_in[6];
    float* out = (float*)d_out;

    const int N = in_sizes[0] / D;   // 50000
    const int E = in_sizes[1];       // 800000
    const int NB = (N + 255) >> 8;   // 196 coarse buckets (<=256 required)

    // ws carve-up
    ushort_t* m1bf   = (ushort_t*)d_ws;                 // N*D
    ushort_t* agg1bf = m1bf + (size_t)N * D;            // N*D
    ushort_t* m2bf   = agg1bf + (size_t)N * D;          // N*D
    ushort_t* W1p    = m2bf + (size_t)N * D;            // 16384
    ushort_t* W2p    = W1p + 16384;                     // 32768
    int*  mat  = (int*)(W2p + 32768);                   // NB*CBLK (histograms)
    int*  matc = mat + (size_t)NB * CBLK;               // NB*CBLK (cursors)
    int*  bb   = matc + (size_t)NB * CBLK;              // NB+1
    int*  offs = bb + NB + 1;                           // N+1
    int2* tmp  = (int2*)(offs + N + 1);                 // E pairs
    int*  bsrc = (int*)(tmp + (size_t)E);               // E

    const int gemmBlocks = (N + 63) / 64;               // 782 (64-row tiles)
    const int gbA = gemmBlocks / 2;                     // gemm1 share in K3

    // K1: weight pack || coarse histogram
    packw_binA<<<CBLK + 24, 256, 0, stream>>>(W1, W2, W1p, W2p, dst, mat, E, NB);
    // K2: merged scans -> bucket bases (bb) + per-block cursors (matc)
    binB<<<NB, 256, 0, stream>>>(mat, matc, bb, offs, E, N, NB);
    // K3: coarse binning || gemm1 tiles [0, gbA)
    binC_gemm1<<<CBLK + gbA, 256, 0, stream>>>(src, dst, matc, tmp, E, NB,
                                               features, W1p, b1, m1bf, N);
    // K4: fine sort (4 subs/bucket) || gemm1 tiles [gbA, gemmBlocks)
    binD_gemm1<<<NB * 4 + (gemmBlocks - gbA), 256, 0, stream>>>(
        tmp, bb, offs, bsrc, N, NB, features, W1p, b1, m1bf, gbA);
    // K5: layer-1 gather -> agg1bf (bf16)
    gather_bf<<<(N * 64 + 255) / 256, 256, 0, stream>>>(m1bf, offs, bsrc,
                                                        agg1bf, nullptr, N);
    // K6: layer-2 GEMM -> out[:,128:] fp32 + m2bf
    gemm2_mfma<<<gemmBlocks, 256, 0, stream>>>(agg1bf, m1bf, W2p, b2,
                                               out + D, m2bf, N);
    // K7: layer-2 gather -> out[:, :128]
    gather_bf<<<(N * 64 + 255) / 256, 256, 0, stream>>>(m2bf, offs, bsrc,
                                                        nullptr, out, N);
}